// Round 13
// baseline (29.872 us; speedup 1.0000x reference)
//
#include <hip/hip_runtime.h>

// RandomResizedCrop N=128,C=3,H=W=256 fp32 — R13: dispatch-rate test.
// R9's per-wave work exactly, but 16 independent waves per 1024-thread block
// -> 2048 WGs instead of 8192 (same total waves, no cross-wave coupling).
// XCD-pinned: image n = (b&7) + 8*(slot>>4); block owns rows k*16..k*16+15.

constexpr int N_ = 128, C_ = 3, H_ = 256, W_ = 256, HW_ = H_ * W_;
constexpr int SEG_ = 264;   // skewed V-segment: x + (x>>5) maps 0..255 -> 0..262

typedef float f32x4 __attribute__((ext_vector_type(4)));

__device__ __forceinline__ void coord(float scale, float bias, float xf, int size,
                                      int& i0, float& w) {
    const float span = (float)size;
    const float two  = 2.0f * span;
    float xs  = (xf + 0.5f) * (2.0f / span) - 1.0f;
    float g   = scale * xs + bias;
    float pre = ((g + 1.0f) * span - 1.0f) * 0.5f;
    float t = fabsf(pre + 0.5f);
    t = t - two * floorf(t * (1.0f / two));   // exact fmod(t, 512), pow2 span
    t = (t > span) ? (two - t) : t;
    t -= 0.5f;
    t = fminf(fmaxf(t, 0.0f), span - 1.0f);
    float f = floorf(t);
    w  = t - f;
    i0 = (int)f;                              // i0 == size-1  =>  w == 0 exactly
}

__global__ __launch_bounds__(1024)
void rrc_kernel(const float* __restrict__ in, const float* __restrict__ wh,
                float* __restrict__ out) {
    __shared__ float V[16 * C_ * SEG_];       // 48 wave-private segments, 50.7 KB
    const int b    = blockIdx.x;
    const int slot = b >> 3;                  // 0..255
    const int n    = (b & 7) + 8 * (slot >> 4);   // image, pinned to XCD b&7
    const int k    = slot & 15;               // 16-row chunk
    const int tid  = threadIdx.x;
    const int wv   = tid >> 6;                // wave 0..15, fully independent
    const int xq   = tid & 63;                // x-quad: x = 4*xq..4*xq+3
    const int y    = k * 16 + wv;             // own output row

    const float w_s = wh[n * 4 + 0];
    const float h_s = wh[n * 4 + 1];
    const float w_b = wh[n * 4 + 2];
    const float h_b = wh[n * 4 + 3];

    // Own row's y-coordinate.
    int iy0; float wy;
    coord(h_s, h_b, (float)y, H_, iy0, wy);
    const int iy1 = min(iy0 + 1, H_ - 1);     // wy==0 when clamped

    // x-coords + skewed gather offsets (addr(x) = x + (x>>5), bijective).
    int offA[4], offB[4]; float wx[4];
#pragma unroll
    for (int j = 0; j < 4; ++j) {
        int i0;
        coord(w_s, w_b, (float)(xq * 4 + j), W_, i0, wx[j]);
        const int xb = min(i0 + 1, W_ - 1);   // wx==0 when clamped
        offA[j] = i0 + (i0 >> 5);
        offB[j] = xb + (xb >> 5);
    }

    // Preload all 3 channels' row pairs (6 coalesced f32x4 loads in flight).
    const float* __restrict__ inN = in + (size_t)n * C_ * HW_;
    f32x4 g0[C_], g1[C_];
#pragma unroll
    for (int c = 0; c < C_; ++c) {
        g0[c] = *reinterpret_cast<const f32x4*>(inN + c * HW_ + iy0 * W_ + xq * 4);
        g1[c] = *reinterpret_cast<const f32x4*>(inN + c * HW_ + iy1 * W_ + xq * 4);
    }

    float* __restrict__ outN = out + (size_t)n * C_ * HW_;
    const int segBase = wv * C_ * SEG_;
    const int woff    = xq * 4 + (xq >> 3);   // skewed write offset

#pragma unroll
    for (int c = 0; c < C_; ++c) {
        const f32x4 v = g0[c] + wy * (g1[c] - g0[c]);   // vlerp in registers
        float* seg = &V[segBase + c * SEG_];
        *reinterpret_cast<f32x4*>(seg + woff) = v;      // 1 ds_write_b128
        f32x4 o;
#pragma unroll
        for (int j = 0; j < 4; ++j) {
            const float a  = seg[offA[j]];
            const float b2 = seg[offB[j]];
            o[j] = a + wx[j] * (b2 - a);                // hlerp
        }
        *reinterpret_cast<f32x4*>(outN + (c * H_ + y) * W_ + xq * 4) = o;
    }
}

extern "C" void kernel_launch(void* const* d_in, const int* in_sizes, int n_in,
                              void* d_out, int out_size, void* d_ws, size_t ws_size,
                              hipStream_t stream) {
    const float* in = (const float*)d_in[0];
    const float* wh = (const float*)d_in[1];
    float* out      = (float*)d_out;
    (void)in_sizes; (void)n_in; (void)out_size; (void)d_ws; (void)ws_size;

    dim3 grid(N_ * 16);   // 2048 WGs x 1024 threads; 16 independent waves each
    dim3 block(1024);
    rrc_kernel<<<grid, block, 0, stream>>>(in, wh, out);
}